// Round 17
// baseline (115.816 us; speedup 1.0000x reference)
//
#include <hip/hip_runtime.h>

typedef unsigned short u16;
typedef unsigned int   u32;
typedef __attribute__((ext_vector_type(4)))  float  f32x4;
typedef __attribute__((ext_vector_type(16))) float  f32x16;
typedef __attribute__((ext_vector_type(8)))  __bf16 bf16x8;
typedef __attribute__((ext_vector_type(8)))  u16    u16x8;
typedef __attribute__((ext_vector_type(2)))  u32    u32x2;
typedef __attribute__((ext_vector_type(4)))  u32    u32x4;

#define GLB_AS __attribute__((address_space(1)))
#define LDS_AS __attribute__((address_space(3)))

__device__ __forceinline__ void gload16(const void* g, void* l) {
  __builtin_amdgcn_global_load_lds((const GLB_AS u32*)g, (LDS_AS u32*)l, 16, 0, 0);
}

// LDS barrier that waits ONLY lgkmcnt (attn reg-staged path; R10/R11/R15/R16-verified).
__device__ __forceinline__ void lds_bar() {
  __builtin_amdgcn_sched_barrier(0);
  asm volatile("s_waitcnt lgkmcnt(0)" ::: "memory");
  __builtin_amdgcn_sched_barrier(0);
  __builtin_amdgcn_s_barrier();
  __builtin_amdgcn_sched_barrier(0);
}

__device__ __forceinline__ u16 f2bf(float f) {
  u32 x = __builtin_bit_cast(u32, f);
  return (u16)((x + 0x7fffu + ((x >> 16) & 1u)) >> 16);
}
__device__ __forceinline__ float bf2f(u16 h) {
  u32 x = ((u32)h) << 16;
  return __builtin_bit_cast(float, x);
}
// packed f32x2 -> bf16x2 (RNE), lo = a, hi = b
__device__ __forceinline__ u32 cvtpk_bf16(float a, float b) {
  u32 r;
  asm("v_cvt_pk_bf16_f32 %0, %1, %2" : "=v"(r) : "v"(a), "v"(b));
  return r;
}

// ---------------- fused cast fp32 -> bf16 (all 7 arrays; R11/R15/R16-verified) -----
__global__ void cast_all(const float* __restrict__ q, const float* __restrict__ k,
                         const float* __restrict__ v, const float* __restrict__ Wq,
                         const float* __restrict__ Wk, const float* __restrict__ Wv,
                         const float* __restrict__ Wo,
                         u16* __restrict__ qb, u16* __restrict__ kb, u16* __restrict__ vb,
                         u16* __restrict__ Wqb, u16* __restrict__ Wkb, u16* __restrict__ Wvb,
                         u16* __restrict__ Wob) {
  int i = blockIdx.x * 256 + threadIdx.x;     // float4 index; total 4,194,304
  const float* src;
  u16* dst;
  int off;
  if (i < 3145728) {
    int seg = i >> 20;
    off = i & 1048575;
    src = seg == 0 ? q : seg == 1 ? k : v;
    dst = seg == 0 ? qb : seg == 1 ? kb : vb;
  } else {
    int wi = i - 3145728;
    int seg = wi >> 18;
    off = wi & 262143;
    src = seg == 0 ? Wq : seg == 1 ? Wk : seg == 2 ? Wv : Wo;
    dst = seg == 0 ? Wqb : seg == 1 ? Wkb : seg == 2 ? Wvb : Wob;
  }
  float4 f = reinterpret_cast<const float4*>(src)[off];
  ushort4 o;
  o.x = f2bf(f.x); o.y = f2bf(f.y); o.z = f2bf(f.z); o.w = f2bf(f.w);
  reinterpret_cast<ushort4*>(dst)[off] = o;
}

// ---------------- GEMM core: BK=64, plain 2-barrier, gload_lds, swizzled (R8-proven)
__device__ __forceinline__ void gemm_core(const u16* __restrict__ Ag, const u16* __restrict__ Bg,
                                          int K, int m0, int n0,
                                          u16* Al, u16* Bl, f32x4 acc[4][4]) {
  const int t = threadIdx.x;
  const int l = t & 63;
  const int c = l & 15, g = l >> 4;
  const int w = t >> 6, wr = w >> 1, wc = w & 1;

#pragma unroll
  for (int mi = 0; mi < 4; mi++)
#pragma unroll
    for (int ni = 0; ni < 4; ni++) acc[mi][ni] = f32x4{0.f, 0.f, 0.f, 0.f};

  for (int k0 = 0; k0 < K; k0 += 64) {
#pragma unroll
    for (int i = 0; i < 4; i++) {
      int idx = i * 256 + t;
      int row = idx >> 3;                      // 0..127
      int oct = (idx & 7) ^ (row & 7);         // pre-swizzled global octet
      gload16(Ag + (size_t)(m0 + row) * K + k0 + oct * 8, Al + (i * 256 + (t & 192)) * 8);
      gload16(Bg + (size_t)(n0 + row) * K + k0 + oct * 8, Bl + (i * 256 + (t & 192)) * 8);
    }
    __syncthreads();

#pragma unroll
    for (int kk = 0; kk < 2; kk++) {
      bf16x8 af[4], bfr[4];
#pragma unroll
      for (int mi = 0; mi < 4; mi++) {
        const int row = wr * 64 + mi * 16 + c;
        af[mi] = *(const bf16x8*)((const char*)Al + row * 128 +
                                  (((kk * 4 + g) ^ (row & 7)) * 16));
      }
#pragma unroll
      for (int ni = 0; ni < 4; ni++) {
        const int row = wc * 64 + ni * 16 + c;
        bfr[ni] = *(const bf16x8*)((const char*)Bl + row * 128 +
                                   (((kk * 4 + g) ^ (row & 7)) * 16));
      }
#pragma unroll
      for (int mi = 0; mi < 4; mi++)
#pragma unroll
        for (int ni = 0; ni < 4; ni++)
          acc[mi][ni] = __builtin_amdgcn_mfma_f32_16x16x32_bf16(af[mi], bfr[ni], acc[mi][ni], 0, 0, 0);
    }
    __syncthreads();
  }
}

// ---------------- fused QKV projection (bf16 in, XCD-contiguous tiles; R11) --------
__global__ __launch_bounds__(256, 4) void qkv_gemm(
    const u16* __restrict__ qb, const u16* __restrict__ kb, const u16* __restrict__ vb,
    const u16* __restrict__ Wqb, const u16* __restrict__ Wkb, const u16* __restrict__ Wvb,
    const float* __restrict__ bq, const float* __restrict__ bk, const float* __restrict__ bv,
    u16* __restrict__ Qp, u16* __restrict__ Kp, u16* __restrict__ Vt) {
  __shared__ alignas(16) u16 Al[128 * 64];
  __shared__ alignas(16) u16 Bl[128 * 64];
  const int fid = blockIdx.x;
  const int g   = (fid & 7) * 96 + (fid >> 3);
  const int z   = g >> 8, r = g & 255;
  const u16 *Ag, *Bg;
  const float* bias;
  if (z == 0)      { Ag = qb;  Bg = Wqb; bias = bq; }
  else if (z == 1) { Ag = kb;  Bg = Wkb; bias = bk; }
  else             { Ag = Wvb; Bg = vb;  bias = bv; }
  int mt, nt;
  if (z < 2) { mt = r >> 3; nt = r & 7; }
  else       { mt = r & 7;  nt = r >> 3; }
  const int m0 = mt * 128, n0 = nt * 128;

  f32x4 acc[4][4];
  gemm_core(Ag, Bg, 1024, m0, n0, Al, Bl, acc);

  const int t = threadIdx.x, l = t & 63, w = t >> 6;
  const int c = l & 15, gg = l >> 4, wr = w >> 1, wc = w & 1;
#pragma unroll
  for (int mi = 0; mi < 4; mi++) {
#pragma unroll
    for (int ni = 0; ni < 4; ni++) {
      const int gcol = n0 + wc * 64 + ni * 16 + c;
#pragma unroll
      for (int rr = 0; rr < 4; rr++) {
        const int grow = m0 + wr * 64 + mi * 16 + gg * 4 + rr;
        float val = acc[mi][ni][rr];
        if (z < 2) {
          val += bias[gcol];
          u16* out = (z == 0) ? Qp : Kp;
          out[(size_t)grow * 1024 + gcol] = f2bf(val);
        } else {
          val += bias[grow];
          const int hh = grow >> 6, dk = grow & 63, bb = gcol >> 11, ss = gcol & 2047;
          Vt[(((size_t)(bb * 16 + hh) * 64 + dk) << 11) + ss] = f2bf(val);
        }
      }
    }
  }
}

// ---------------- final output projection (fp32 out; R11) ----------------
__global__ __launch_bounds__(256, 4) void out_gemm(
    const u16* __restrict__ AO, const u16* __restrict__ Wob,
    const float* __restrict__ bo, float* __restrict__ out) {
  __shared__ alignas(16) u16 Al[128 * 64];
  __shared__ alignas(16) u16 Bl[128 * 64];
  const int fid = blockIdx.x;
  const int g   = (fid & 7) * 32 + (fid >> 3);    // XCD-contiguous
  const int m0  = (g >> 3) * 128, n0 = (g & 7) * 128;
  f32x4 acc[4][4];
  gemm_core(AO, Wob, 1024, m0, n0, Al, Bl, acc);
  const int t = threadIdx.x, l = t & 63, w = t >> 6;
  const int c = l & 15, gg = l >> 4, wr = w >> 1, wc = w & 1;
#pragma unroll
  for (int mi = 0; mi < 4; mi++)
#pragma unroll
    for (int ni = 0; ni < 4; ni++) {
      const int gcol = n0 + wc * 64 + ni * 16 + c;
      const float bb = bo[gcol];
#pragma unroll
      for (int rr = 0; rr < 4; rr++) {
        const int grow = m0 + wr * 64 + mi * 16 + gg * 4 + rr;
        out[(size_t)grow * 1024 + gcol] = acc[mi][ni][rr] + bb;
      }
    }
}

// ---------------- flash attention v12: R16 template + tree-reduced softmax sum -----
// Only delta vs R16 (verified 50.4 us): the per-tile probability sum is computed
// as a pairwise tree (depth 6) instead of a 64-deep serial dependent-add chain.
// Positive summands -> tree is at least as accurate; absmax can only improve.
__global__ __launch_bounds__(256, 2) void attn_fwd(
    const u16* __restrict__ Qb, const u16* __restrict__ Kb,
    const u16* __restrict__ Vt, u16* __restrict__ AO) {
  __shared__ alignas(16) u16 Kl[2][128 * 64];
  __shared__ alignas(16) u16 Vl[2][64 * 128];
  const int bh = blockIdx.x, b = bh >> 4, h = bh & 15;
  const int q0 = blockIdx.y * 128;
  const int t = threadIdx.x, w = t >> 6, l = t & 63;
  const int q = l & 31, hi = l >> 5;

  u16x8 kreg[4], vreg[4];
  auto issue = [&](int kv) {
#pragma unroll
    for (int i = 0; i < 4; i++) {
      const int ik = i * 256 + t, krow = ik >> 3, koct = ik & 7;
      kreg[i] = *(const u16x8*)(Kb + (size_t)(b * 2048 + kv + krow) * 1024 + h * 64 + koct * 8);
      const int iv = i * 256 + t, vrow = iv >> 4, vp = iv & 15;
      vreg[i] = *(const u16x8*)(Vt + (size_t)(bh * 64 + vrow) * 2048 + kv + vp * 8);
    }
  };
  auto commit = [&](int bb) {
#pragma unroll
    for (int i = 0; i < 4; i++) {
      const int ik = i * 256 + t, krow = ik >> 3;
      const int koct = (ik & 7) ^ (krow & 7);
      *(u16x8*)(Kl[bb] + krow * 64 + koct * 8) = kreg[i];
      const int iv = i * 256 + t, vrow = iv >> 4, vp = iv & 15;
      const int sp = (vp & 8) | ((vp & 7) ^ (vrow & 7));
      *(u16x8*)(Vl[bb] + vrow * 128 + sp * 8) = vreg[i];
    }
  };

  issue(0);

  // Q fragments: B-operand of 32x32x16, col q, k-octet = hi. Pre-scaled log2(e)/8.
  const float QSCALE = 0.125f * 1.44269504f;
  bf16x8 qf[4];
  {
    const u16* qp = Qb + ((size_t)(b * 2048 + q0 + w * 32 + q) * 1024 + h * 64);
#pragma unroll
    for (int ks = 0; ks < 4; ks++) {
      u16x8 raw = *(const u16x8*)(qp + ks * 16 + hi * 8);
      u16x8 sc;
#pragma unroll
      for (int j = 0; j < 8; j++) sc[j] = f2bf(bf2f(raw[j]) * QSCALE);
      qf[ks] = __builtin_bit_cast(bf16x8, sc);
    }
  }

  f32x16 oT[2];
#pragma unroll
  for (int dt = 0; dt < 2; dt++)
#pragma unroll
    for (int rr = 0; rr < 16; rr++) oT[dt][rr] = 0.f;
  float lsum = 0.f;

  for (int it = 0; it < 16; it++) {
    const int cur = it & 1;
    commit(cur);
    if (it + 1 < 16) issue((it + 1) * 128);   // loads float across the barrier
    lds_bar();

    // QK^T: st[ni] covers kv rows ni*32..ni*32+31 (log2 units)
    f32x16 st[4];
#pragma unroll
    for (int ni = 0; ni < 4; ni++) {
#pragma unroll
      for (int rr = 0; rr < 16; rr++) st[ni][rr] = 0.f;
      __builtin_amdgcn_s_setprio(1);
#pragma unroll
      for (int ks = 0; ks < 4; ks++) {
        const int krow = ni * 32 + q;
        bf16x8 kf = *(const bf16x8*)((const char*)Kl[cur] + krow * 128 +
                                     (((ks * 2 + hi) * 16) ^ ((krow & 7) << 4)));
        st[ni] = __builtin_amdgcn_mfma_f32_32x32x16_bf16(kf, qf[ks], st[ni], 0, 0, 0);
      }
      __builtin_amdgcn_s_setprio(0);
    }

    // P = exp2(st); tree-reduced sum; pack + permlane32_swap into PV frags pf[0..7]
    bf16x8 pf[8];
    float tn[4];
#pragma unroll
    for (int ni = 0; ni < 4; ni++) {
      float p[16];
#pragma unroll
      for (int rr = 0; rr < 16; rr++)
        p[rr] = __builtin_amdgcn_exp2f(st[ni][rr]);
      // pairwise tree (depth 4 within group) instead of serial chain
      float g0 = (p[0] + p[1]) + (p[2] + p[3]);
      float g1 = (p[4] + p[5]) + (p[6] + p[7]);
      float g2 = (p[8] + p[9]) + (p[10] + p[11]);
      float g3 = (p[12] + p[13]) + (p[14] + p[15]);
      tn[ni] = (g0 + g1) + (g2 + g3);
#pragma unroll
      for (int pp = 0; pp < 2; pp++) {
        u32 Wa = cvtpk_bf16(p[8 * pp + 0], p[8 * pp + 1]);
        u32 Wb = cvtpk_bf16(p[8 * pp + 2], p[8 * pp + 3]);
        u32 Wc = cvtpk_bf16(p[8 * pp + 4], p[8 * pp + 5]);
        u32 Wd = cvtpk_bf16(p[8 * pp + 6], p[8 * pp + 7]);
        u32x2 r0 = __builtin_amdgcn_permlane32_swap(Wa, Wc, false, false);  // {w0, w2}
        u32x2 r1 = __builtin_amdgcn_permlane32_swap(Wb, Wd, false, false);  // {w1, w3}
        u32x4 fw;
        fw.x = r0.x; fw.y = r1.x; fw.z = r0.y; fw.w = r1.y;
        pf[ni * 2 + pp] = __builtin_bit_cast(bf16x8, fw);
      }
    }
    lsum += (tn[0] + tn[1]) + (tn[2] + tn[3]);

    // PV: oT[dt] += V^T x P^T over 8 kv-slices
#pragma unroll
    for (int dt = 0; dt < 2; dt++) {
      __builtin_amdgcn_s_setprio(1);
#pragma unroll
      for (int ks = 0; ks < 8; ks++) {
        const int vrow = dt * 32 + q;
        bf16x8 vf = *(const bf16x8*)((const char*)Vl[cur] + vrow * 256 +
                                     (((ks * 2 + hi) * 16) ^ ((vrow & 7) << 4)));
        oT[dt] = __builtin_amdgcn_mfma_f32_32x32x16_bf16(vf, pf[ks], oT[dt], 0, 0, 0);
      }
      __builtin_amdgcn_s_setprio(0);
    }
  }

  // epilogue: reduce lsum across halves, scale, store packed pairs
  lsum += __shfl_xor(lsum, 32);
  const float li = 1.f / lsum;
  u16* aop = AO + (size_t)(b * 2048 + q0 + w * 32 + q) * 1024 + h * 64;
#pragma unroll
  for (int dt = 0; dt < 2; dt++)
#pragma unroll
    for (int rq = 0; rq < 4; rq++) {
      const int dbase = dt * 32 + rq * 8 + hi * 4;
      u32x2 pr;
      pr.x = cvtpk_bf16(oT[dt][4 * rq + 0] * li, oT[dt][4 * rq + 1] * li);
      pr.y = cvtpk_bf16(oT[dt][4 * rq + 2] * li, oT[dt][4 * rq + 3] * li);
      *(u32x2*)(aop + dbase) = pr;
    }
}

// ================== launch ==================
extern "C" void kernel_launch(void* const* d_in, const int* in_sizes, int n_in,
                              void* d_out, int out_size, void* d_ws, size_t ws_size,
                              hipStream_t stream) {
  const float* q  = (const float*)d_in[0];
  const float* k  = (const float*)d_in[1];
  const float* v  = (const float*)d_in[2];
  const float* Wq = (const float*)d_in[3];
  const float* bq = (const float*)d_in[4];
  const float* Wk = (const float*)d_in[5];
  const float* bk = (const float*)d_in[6];
  const float* Wv = (const float*)d_in[7];
  const float* bv = (const float*)d_in[8];
  const float* Wo = (const float*)d_in[9];
  const float* bo = (const float*)d_in[10];

  char* ws = (char*)d_ws;
  const size_t MB = 1u << 20;
  u16* qb  = (u16*)(ws + 0 * MB);
  u16* kb  = (u16*)(ws + 8 * MB);
  u16* vb  = (u16*)(ws + 16 * MB);
  u16* Wqb = (u16*)(ws + 24 * MB);
  u16* Wkb = (u16*)(ws + 26 * MB);
  u16* Wvb = (u16*)(ws + 28 * MB);
  u16* Wob = (u16*)(ws + 30 * MB);
  u16* Qp  = (u16*)(ws + 32 * MB);
  u16* Kp  = (u16*)(ws + 40 * MB);
  u16* Vtp = (u16*)(ws + 48 * MB);
  u16* AO  = (u16*)(ws + 56 * MB);

  cast_all<<<16384, 256, 0, stream>>>(q, k, v, Wq, Wk, Wv, Wo,
                                      qb, kb, vb, Wqb, Wkb, Wvb, Wob);
  qkv_gemm<<<768, 256, 0, stream>>>(qb, kb, vb, Wqb, Wkb, Wvb,
                                    bq, bk, bv, Qp, Kp, Vtp);
  attn_fwd<<<dim3(32, 16), 256, 0, stream>>>(Qp, Kp, Vtp, AO);
  out_gemm<<<256, 256, 0, stream>>>(AO, Wob, bo, (float*)d_out);
}

// Round 18
// 115.104 us; speedup vs baseline: 1.0062x; 1.0062x over previous
//
#include <hip/hip_runtime.h>

typedef unsigned short u16;
typedef unsigned int   u32;
typedef __attribute__((ext_vector_type(4)))  float  f32x4;
typedef __attribute__((ext_vector_type(16))) float  f32x16;
typedef __attribute__((ext_vector_type(8)))  __bf16 bf16x8;
typedef __attribute__((ext_vector_type(8)))  u16    u16x8;
typedef __attribute__((ext_vector_type(2)))  u32    u32x2;
typedef __attribute__((ext_vector_type(4)))  u32    u32x4;

#define GLB_AS __attribute__((address_space(1)))
#define LDS_AS __attribute__((address_space(3)))

__device__ __forceinline__ void gload16(const void* g, void* l) {
  __builtin_amdgcn_global_load_lds((const GLB_AS u32*)g, (LDS_AS u32*)l, 16, 0, 0);
}

// LDS barrier that waits ONLY lgkmcnt (attn reg-staged path; R10/R11/R15/R16-verified).
__device__ __forceinline__ void lds_bar() {
  __builtin_amdgcn_sched_barrier(0);
  asm volatile("s_waitcnt lgkmcnt(0)" ::: "memory");
  __builtin_amdgcn_sched_barrier(0);
  __builtin_amdgcn_s_barrier();
  __builtin_amdgcn_sched_barrier(0);
}

__device__ __forceinline__ u16 f2bf(float f) {
  u32 x = __builtin_bit_cast(u32, f);
  return (u16)((x + 0x7fffu + ((x >> 16) & 1u)) >> 16);
}
__device__ __forceinline__ float bf2f(u16 h) {
  u32 x = ((u32)h) << 16;
  return __builtin_bit_cast(float, x);
}
// packed f32x2 -> bf16x2 (RNE), lo = a, hi = b
__device__ __forceinline__ u32 cvtpk_bf16(float a, float b) {
  u32 r;
  asm("v_cvt_pk_bf16_f32 %0, %1, %2" : "=v"(r) : "v"(a), "v"(b));
  return r;
}

// ---------------- fused cast fp32 -> bf16 (all 7 arrays; R11/R15/R16-verified) -----
__global__ void cast_all(const float* __restrict__ q, const float* __restrict__ k,
                         const float* __restrict__ v, const float* __restrict__ Wq,
                         const float* __restrict__ Wk, const float* __restrict__ Wv,
                         const float* __restrict__ Wo,
                         u16* __restrict__ qb, u16* __restrict__ kb, u16* __restrict__ vb,
                         u16* __restrict__ Wqb, u16* __restrict__ Wkb, u16* __restrict__ Wvb,
                         u16* __restrict__ Wob) {
  int i = blockIdx.x * 256 + threadIdx.x;     // float4 index; total 4,194,304
  const float* src;
  u16* dst;
  int off;
  if (i < 3145728) {
    int seg = i >> 20;
    off = i & 1048575;
    src = seg == 0 ? q : seg == 1 ? k : v;
    dst = seg == 0 ? qb : seg == 1 ? kb : vb;
  } else {
    int wi = i - 3145728;
    int seg = wi >> 18;
    off = wi & 262143;
    src = seg == 0 ? Wq : seg == 1 ? Wk : seg == 2 ? Wv : Wo;
    dst = seg == 0 ? Wqb : seg == 1 ? Wkb : seg == 2 ? Wvb : Wob;
  }
  float4 f = reinterpret_cast<const float4*>(src)[off];
  ushort4 o;
  o.x = f2bf(f.x); o.y = f2bf(f.y); o.z = f2bf(f.z); o.w = f2bf(f.w);
  reinterpret_cast<ushort4*>(dst)[off] = o;
}

// ---------------- GEMM core: BK=64, plain 2-barrier, gload_lds, swizzled (R8-proven)
__device__ __forceinline__ void gemm_core(const u16* __restrict__ Ag, const u16* __restrict__ Bg,
                                          int K, int m0, int n0,
                                          u16* Al, u16* Bl, f32x4 acc[4][4]) {
  const int t = threadIdx.x;
  const int l = t & 63;
  const int c = l & 15, g = l >> 4;
  const int w = t >> 6, wr = w >> 1, wc = w & 1;

#pragma unroll
  for (int mi = 0; mi < 4; mi++)
#pragma unroll
    for (int ni = 0; ni < 4; ni++) acc[mi][ni] = f32x4{0.f, 0.f, 0.f, 0.f};

  for (int k0 = 0; k0 < K; k0 += 64) {
#pragma unroll
    for (int i = 0; i < 4; i++) {
      int idx = i * 256 + t;
      int row = idx >> 3;                      // 0..127
      int oct = (idx & 7) ^ (row & 7);         // pre-swizzled global octet
      gload16(Ag + (size_t)(m0 + row) * K + k0 + oct * 8, Al + (i * 256 + (t & 192)) * 8);
      gload16(Bg + (size_t)(n0 + row) * K + k0 + oct * 8, Bl + (i * 256 + (t & 192)) * 8);
    }
    __syncthreads();

#pragma unroll
    for (int kk = 0; kk < 2; kk++) {
      bf16x8 af[4], bfr[4];
#pragma unroll
      for (int mi = 0; mi < 4; mi++) {
        const int row = wr * 64 + mi * 16 + c;
        af[mi] = *(const bf16x8*)((const char*)Al + row * 128 +
                                  (((kk * 4 + g) ^ (row & 7)) * 16));
      }
#pragma unroll
      for (int ni = 0; ni < 4; ni++) {
        const int row = wc * 64 + ni * 16 + c;
        bfr[ni] = *(const bf16x8*)((const char*)Bl + row * 128 +
                                   (((kk * 4 + g) ^ (row & 7)) * 16));
      }
#pragma unroll
      for (int mi = 0; mi < 4; mi++)
#pragma unroll
        for (int ni = 0; ni < 4; ni++)
          acc[mi][ni] = __builtin_amdgcn_mfma_f32_16x16x32_bf16(af[mi], bfr[ni], acc[mi][ni], 0, 0, 0);
    }
    __syncthreads();
  }
}

// ---------------- fused QKV projection (bf16 in, XCD-contiguous tiles; R11) --------
__global__ __launch_bounds__(256, 4) void qkv_gemm(
    const u16* __restrict__ qb, const u16* __restrict__ kb, const u16* __restrict__ vb,
    const u16* __restrict__ Wqb, const u16* __restrict__ Wkb, const u16* __restrict__ Wvb,
    const float* __restrict__ bq, const float* __restrict__ bk, const float* __restrict__ bv,
    u16* __restrict__ Qp, u16* __restrict__ Kp, u16* __restrict__ Vt) {
  __shared__ alignas(16) u16 Al[128 * 64];
  __shared__ alignas(16) u16 Bl[128 * 64];
  const int fid = blockIdx.x;
  const int g   = (fid & 7) * 96 + (fid >> 3);
  const int z   = g >> 8, r = g & 255;
  const u16 *Ag, *Bg;
  const float* bias;
  if (z == 0)      { Ag = qb;  Bg = Wqb; bias = bq; }
  else if (z == 1) { Ag = kb;  Bg = Wkb; bias = bk; }
  else             { Ag = Wvb; Bg = vb;  bias = bv; }
  int mt, nt;
  if (z < 2) { mt = r >> 3; nt = r & 7; }
  else       { mt = r & 7;  nt = r >> 3; }
  const int m0 = mt * 128, n0 = nt * 128;

  f32x4 acc[4][4];
  gemm_core(Ag, Bg, 1024, m0, n0, Al, Bl, acc);

  const int t = threadIdx.x, l = t & 63, w = t >> 6;
  const int c = l & 15, gg = l >> 4, wr = w >> 1, wc = w & 1;
#pragma unroll
  for (int mi = 0; mi < 4; mi++) {
#pragma unroll
    for (int ni = 0; ni < 4; ni++) {
      const int gcol = n0 + wc * 64 + ni * 16 + c;
#pragma unroll
      for (int rr = 0; rr < 4; rr++) {
        const int grow = m0 + wr * 64 + mi * 16 + gg * 4 + rr;
        float val = acc[mi][ni][rr];
        if (z < 2) {
          val += bias[gcol];
          u16* out = (z == 0) ? Qp : Kp;
          out[(size_t)grow * 1024 + gcol] = f2bf(val);
        } else {
          val += bias[grow];
          const int hh = grow >> 6, dk = grow & 63, bb = gcol >> 11, ss = gcol & 2047;
          Vt[(((size_t)(bb * 16 + hh) * 64 + dk) << 11) + ss] = f2bf(val);
        }
      }
    }
  }
}

// ---------------- final output projection (fp32 out; R11) ----------------
__global__ __launch_bounds__(256, 4) void out_gemm(
    const u16* __restrict__ AO, const u16* __restrict__ Wob,
    const float* __restrict__ bo, float* __restrict__ out) {
  __shared__ alignas(16) u16 Al[128 * 64];
  __shared__ alignas(16) u16 Bl[128 * 64];
  const int fid = blockIdx.x;
  const int g   = (fid & 7) * 32 + (fid >> 3);    // XCD-contiguous
  const int m0  = (g >> 3) * 128, n0 = (g & 7) * 128;
  f32x4 acc[4][4];
  gemm_core(AO, Wob, 1024, m0, n0, Al, Bl, acc);
  const int t = threadIdx.x, l = t & 63, w = t >> 6;
  const int c = l & 15, gg = l >> 4, wr = w >> 1, wc = w & 1;
#pragma unroll
  for (int mi = 0; mi < 4; mi++)
#pragma unroll
    for (int ni = 0; ni < 4; ni++) {
      const int gcol = n0 + wc * 64 + ni * 16 + c;
      const float bb = bo[gcol];
#pragma unroll
      for (int rr = 0; rr < 4; rr++) {
        const int grow = m0 + wr * 64 + mi * 16 + gg * 4 + rr;
        out[(size_t)grow * 1024 + gcol] = acc[mi][ni][rr] + bb;
      }
    }
}

// ---------------- flash attention v11 (R16-verified, verbatim): KVBLK=128 ----------
__global__ __launch_bounds__(256, 2) void attn_fwd(
    const u16* __restrict__ Qb, const u16* __restrict__ Kb,
    const u16* __restrict__ Vt, u16* __restrict__ AO) {
  __shared__ alignas(16) u16 Kl[2][128 * 64];
  __shared__ alignas(16) u16 Vl[2][64 * 128];
  const int bh = blockIdx.x, b = bh >> 4, h = bh & 15;
  const int q0 = blockIdx.y * 128;
  const int t = threadIdx.x, w = t >> 6, l = t & 63;
  const int q = l & 31, hi = l >> 5;

  u16x8 kreg[4], vreg[4];
  auto issue = [&](int kv) {
#pragma unroll
    for (int i = 0; i < 4; i++) {
      const int ik = i * 256 + t, krow = ik >> 3, koct = ik & 7;
      kreg[i] = *(const u16x8*)(Kb + (size_t)(b * 2048 + kv + krow) * 1024 + h * 64 + koct * 8);
      const int iv = i * 256 + t, vrow = iv >> 4, vp = iv & 15;
      vreg[i] = *(const u16x8*)(Vt + (size_t)(bh * 64 + vrow) * 2048 + kv + vp * 8);
    }
  };
  auto commit = [&](int bb) {
#pragma unroll
    for (int i = 0; i < 4; i++) {
      const int ik = i * 256 + t, krow = ik >> 3;
      const int koct = (ik & 7) ^ (krow & 7);
      *(u16x8*)(Kl[bb] + krow * 64 + koct * 8) = kreg[i];
      const int iv = i * 256 + t, vrow = iv >> 4, vp = iv & 15;
      const int sp = (vp & 8) | ((vp & 7) ^ (vrow & 7));
      *(u16x8*)(Vl[bb] + vrow * 128 + sp * 8) = vreg[i];
    }
  };

  issue(0);

  // Q fragments: B-operand of 32x32x16, col q, k-octet = hi. Pre-scaled log2(e)/8.
  const float QSCALE = 0.125f * 1.44269504f;
  bf16x8 qf[4];
  {
    const u16* qp = Qb + ((size_t)(b * 2048 + q0 + w * 32 + q) * 1024 + h * 64);
#pragma unroll
    for (int ks = 0; ks < 4; ks++) {
      u16x8 raw = *(const u16x8*)(qp + ks * 16 + hi * 8);
      u16x8 sc;
#pragma unroll
      for (int j = 0; j < 8; j++) sc[j] = f2bf(bf2f(raw[j]) * QSCALE);
      qf[ks] = __builtin_bit_cast(bf16x8, sc);
    }
  }

  f32x16 oT[2];
#pragma unroll
  for (int dt = 0; dt < 2; dt++)
#pragma unroll
    for (int rr = 0; rr < 16; rr++) oT[dt][rr] = 0.f;
  float lsum = 0.f;

  for (int it = 0; it < 16; it++) {
    const int cur = it & 1;
    commit(cur);
    if (it + 1 < 16) issue((it + 1) * 128);   // loads float across the barrier
    lds_bar();

    // QK^T: st[ni] covers kv rows ni*32..ni*32+31 (log2 units)
    f32x16 st[4];
#pragma unroll
    for (int ni = 0; ni < 4; ni++) {
#pragma unroll
      for (int rr = 0; rr < 16; rr++) st[ni][rr] = 0.f;
      __builtin_amdgcn_s_setprio(1);
#pragma unroll
      for (int ks = 0; ks < 4; ks++) {
        const int krow = ni * 32 + q;
        bf16x8 kf = *(const bf16x8*)((const char*)Kl[cur] + krow * 128 +
                                     (((ks * 2 + hi) * 16) ^ ((krow & 7) << 4)));
        st[ni] = __builtin_amdgcn_mfma_f32_32x32x16_bf16(kf, qf[ks], st[ni], 0, 0, 0);
      }
      __builtin_amdgcn_s_setprio(0);
    }

    // P = exp2(st); pack + permlane32_swap into PV B-operand frags pf[0..7]
    bf16x8 pf[8];
    float ts = 0.f;
#pragma unroll
    for (int ni = 0; ni < 4; ni++) {
      float p[16];
#pragma unroll
      for (int rr = 0; rr < 16; rr++) {
        p[rr] = __builtin_amdgcn_exp2f(st[ni][rr]);
        ts += p[rr];
      }
#pragma unroll
      for (int pp = 0; pp < 2; pp++) {
        u32 Wa = cvtpk_bf16(p[8 * pp + 0], p[8 * pp + 1]);
        u32 Wb = cvtpk_bf16(p[8 * pp + 2], p[8 * pp + 3]);
        u32 Wc = cvtpk_bf16(p[8 * pp + 4], p[8 * pp + 5]);
        u32 Wd = cvtpk_bf16(p[8 * pp + 6], p[8 * pp + 7]);
        u32x2 r0 = __builtin_amdgcn_permlane32_swap(Wa, Wc, false, false);  // {w0, w2}
        u32x2 r1 = __builtin_amdgcn_permlane32_swap(Wb, Wd, false, false);  // {w1, w3}
        u32x4 fw;
        fw.x = r0.x; fw.y = r1.x; fw.z = r0.y; fw.w = r1.y;
        pf[ni * 2 + pp] = __builtin_bit_cast(bf16x8, fw);
      }
    }
    lsum += ts;

    // PV: oT[dt] += V^T x P^T over 8 kv-slices
#pragma unroll
    for (int dt = 0; dt < 2; dt++) {
      __builtin_amdgcn_s_setprio(1);
#pragma unroll
      for (int ks = 0; ks < 8; ks++) {
        const int vrow = dt * 32 + q;
        bf16x8 vf = *(const bf16x8*)((const char*)Vl[cur] + vrow * 256 +
                                     (((ks * 2 + hi) * 16) ^ ((vrow & 7) << 4)));
        oT[dt] = __builtin_amdgcn_mfma_f32_32x32x16_bf16(vf, pf[ks], oT[dt], 0, 0, 0);
      }
      __builtin_amdgcn_s_setprio(0);
    }
  }

  // epilogue: reduce lsum across halves, scale, store packed pairs
  lsum += __shfl_xor(lsum, 32);
  const float li = 1.f / lsum;
  u16* aop = AO + (size_t)(b * 2048 + q0 + w * 32 + q) * 1024 + h * 64;
#pragma unroll
  for (int dt = 0; dt < 2; dt++)
#pragma unroll
    for (int rq = 0; rq < 4; rq++) {
      const int dbase = dt * 32 + rq * 8 + hi * 4;
      u32x2 pr;
      pr.x = cvtpk_bf16(oT[dt][4 * rq + 0] * li, oT[dt][4 * rq + 1] * li);
      pr.y = cvtpk_bf16(oT[dt][4 * rq + 2] * li, oT[dt][4 * rq + 3] * li);
      *(u32x2*)(aop + dbase) = pr;
    }
}

// ================== launch ==================
extern "C" void kernel_launch(void* const* d_in, const int* in_sizes, int n_in,
                              void* d_out, int out_size, void* d_ws, size_t ws_size,
                              hipStream_t stream) {
  const float* q  = (const float*)d_in[0];
  const float* k  = (const float*)d_in[1];
  const float* v  = (const float*)d_in[2];
  const float* Wq = (const float*)d_in[3];
  const float* bq = (const float*)d_in[4];
  const float* Wk = (const float*)d_in[5];
  const float* bk = (const float*)d_in[6];
  const float* Wv = (const float*)d_in[7];
  const float* bv = (const float*)d_in[8];
  const float* Wo = (const float*)d_in[9];
  const float* bo = (const float*)d_in[10];

  char* ws = (char*)d_ws;
  const size_t MB = 1u << 20;
  u16* qb  = (u16*)(ws + 0 * MB);
  u16* kb  = (u16*)(ws + 8 * MB);
  u16* vb  = (u16*)(ws + 16 * MB);
  u16* Wqb = (u16*)(ws + 24 * MB);
  u16* Wkb = (u16*)(ws + 26 * MB);
  u16* Wvb = (u16*)(ws + 28 * MB);
  u16* Wob = (u16*)(ws + 30 * MB);
  u16* Qp  = (u16*)(ws + 32 * MB);
  u16* Kp  = (u16*)(ws + 40 * MB);
  u16* Vtp = (u16*)(ws + 48 * MB);
  u16* AO  = (u16*)(ws + 56 * MB);

  cast_all<<<16384, 256, 0, stream>>>(q, k, v, Wq, Wk, Wv, Wo,
                                      qb, kb, vb, Wqb, Wkb, Wvb, Wob);
  qkv_gemm<<<768, 256, 0, stream>>>(qb, kb, vb, Wqb, Wkb, Wvb,
                                    bq, bk, bv, Qp, Kp, Vtp);
  attn_fwd<<<dim3(32, 16), 256, 0, stream>>>(Qp, Kp, Vtp, AO);
  out_gemm<<<256, 256, 0, stream>>>(AO, Wob, bo, (float*)d_out);
}